// Round 6
// baseline (105.017 us; speedup 1.0000x reference)
//
#include <hip/hip_runtime.h>
#include <hip/hip_fp16.h>
#include <stdint.h>

#define NPTS 2097152
#define BLOCK 256
#define PPT 4
#define NBLK (NPTS / (BLOCK * PPT))   // 2048 blocks

typedef float f32x2 __attribute__((ext_vector_type(2)));

// Pin a wave-uniform float to an SGPR (frees a VGPR; 1 SGPR operand per VALU inst)
static __device__ __forceinline__ float rfl(float v) {
    return __int_as_float(__builtin_amdgcn_readfirstlane(__float_as_int(v)));
}
static __device__ __forceinline__ __half2 u2h(uint32_t u) {
    union { uint32_t i; __half2 h; } v; v.i = u; return v.h;
}
static __device__ __forceinline__ uint32_t h2u(__half2 h) {
    union { __half2 h; uint32_t i; } v; v.h = h; return v.i;
}
static __device__ __forceinline__ f32x2 fma2(f32x2 a, f32x2 b, f32x2 c) {
    return __builtin_elementwise_fma(a, b, c);   // -> v_pk_fma_f32
}
// silu on a point-pair; ONE rcp per pair via reciprocal sharing:
// 1/da = rcp(da*db)*db. Safe: |pre-act| <~ 10 -> d <= ~2e4, product << f32 max.
static __device__ __forceinline__ f32x2 silu2(f32x2 v) {
    f32x2 t = v * (-1.4426950408889634f);
    f32x2 e = { __builtin_amdgcn_exp2f(t.x), __builtin_amdgcn_exp2f(t.y) };
    f32x2 d = e + 1.0f;
    float r = __builtin_amdgcn_rcpf(d.x * d.y);
    f32x2 inv = { r * d.y, r * d.x };
    return v * inv;
}
// LN split: prep computes centered diffs + rsqrt (independent of grid values),
// so the second point's LDS-interp latency hides under it.
static __device__ __forceinline__ void ln2_prep(const f32x2* h, f32x2* d, f32x2* rs) {
    f32x2 mu = (h[0] + h[1] + h[2] + h[3] + h[4] + h[5]) * (1.0f / 6.0f);
    f32x2 var = (f32x2)0.0f;
#pragma unroll
    for (int j = 0; j < 6; ++j) { d[j] = h[j] - mu; var = fma2(d[j], d[j], var); }
    f32x2 vv = var * (1.0f / 6.0f) + 1e-5f;
    f32x2 r = { __builtin_amdgcn_rsqf(vv.x), __builtin_amdgcn_rsqf(vv.y) };
    *rs = r;
}

// ---------------------------------------------------------------------------
// Pre-kernel: build the packed half2 grid image ONCE into workspace.
// Layout (dwords): idx = (l*256 + cell)*12 + slot, slot = {A0,B0,...,A5,B5}.
//   slots s<3  : gamma' = gamma * ln_w     (channel pairs 2s,2s+1)
//   slots s>=3 : beta'  = gamma * ln_b + beta
// A = value at (y,x), B = value at (y,x+1 clamped). 6144 dwords = 24 KB.
// ---------------------------------------------------------------------------
__global__ __launch_bounds__(256) void pack_kernel(
    const float* __restrict__ gamma,
    const float* __restrict__ beta,
    const float* __restrict__ ln_w,
    const float* __restrict__ ln_b,
    uint32_t* __restrict__ ws)
{
    int idx = blockIdx.x * 256 + threadIdx.x;   // 12 blocks x 256 = 3072 items
    if (idx >= 3072) return;
    int l = (idx >= 1536) ? 1 : 0;
    int r = idx - l * 1536;            // 0..1535
    int s = r >> 8;                    // pair 0..5
    int cell = r & 255;
    int x = cell & 15;
    int x1 = (x < 15) ? x + 1 : 15;    // border clamp baked into B
    int rowb = cell - x;               // y*16
    int ch0 = (s < 3) ? 2 * s : 2 * (s - 3);
    const float* gsrc = gamma + l * 1536 + ch0 * 256;
    float ga_lo = gsrc[rowb + x];
    float ga_hi = gsrc[256 + rowb + x];
    float gb_lo = gsrc[rowb + x1];
    float gb_hi = gsrc[256 + rowb + x1];
    float a_lo, a_hi, b_lo, b_hi;
    if (s < 3) {
        float w_lo = ln_w[6 * l + ch0];
        float w_hi = ln_w[6 * l + ch0 + 1];
        a_lo = ga_lo * w_lo; a_hi = ga_hi * w_hi;
        b_lo = gb_lo * w_lo; b_hi = gb_hi * w_hi;
    } else {
        const float* bsrc = beta + l * 1536 + ch0 * 256;
        float nb_lo = ln_b[6 * l + ch0];
        float nb_hi = ln_b[6 * l + ch0 + 1];
        a_lo = fmaf(ga_lo, nb_lo, bsrc[rowb + x]);
        a_hi = fmaf(ga_hi, nb_hi, bsrc[256 + rowb + x]);
        b_lo = fmaf(gb_lo, nb_lo, bsrc[rowb + x1]);
        b_hi = fmaf(gb_hi, nb_hi, bsrc[256 + rowb + x1]);
    }
    uint32_t* dst = ws + (l * 256 + cell) * 12 + 2 * s;
    dst[0] = h2u(__floats2half2_rn(a_lo, a_hi));
    dst[1] = h2u(__floats2half2_rn(b_lo, b_hi));
}

// Accumulate one grid row (3 b128 = A|B half2 pairs for 6 slots) into acc[6].
static __device__ __forceinline__ void interp_row(
    uint4 r0, uint4 r1, uint4 r2, __half2 Wa, __half2 Wb, __half2* acc, bool first)
{
    uint32_t A[6] = { r0.x, r0.z, r1.x, r1.z, r2.x, r2.z };
    uint32_t B[6] = { r0.y, r0.w, r1.y, r1.w, r2.y, r2.w };
#pragma unroll
    for (int s = 0; s < 6; ++s) {
        __half2 t = first ? __hmul2(u2h(A[s]), Wa) : __hfma2(u2h(A[s]), Wa, acc[s]);
        acc[s] = __hfma2(u2h(B[s]), Wb, t);
    }
}

// Full bilinear interp for one point/layer; writes component c of G/Bb.
// Row-split keeps only 3 uint4 + 6 half2 accs live (VGPR diet).
static __device__ __forceinline__ void interp_point(
    const uint4* base, int off, const __half2* W, f32x2* G, f32x2* Bb, int c)
{
    uint4 r0 = base[off], r1 = base[off + 1], r2 = base[off + 2];
    __half2 acc[6];
    interp_row(r0, r1, r2, W[0], W[1], acc, true);
    uint4 s0 = base[off + 48], s1 = base[off + 49], s2 = base[off + 50];
    interp_row(s0, s1, s2, W[2], W[3], acc, false);
#pragma unroll
    for (int s = 0; s < 6; ++s) {
        float2 r = __half22float2(acc[s]);
        if (s < 3) { G[2 * s][c] = r.x; G[2 * s + 1][c] = r.y; }
        else       { Bb[2 * (s - 3)][c] = r.x; Bb[2 * (s - 3) + 1][c] = r.y; }
    }
}

// Coordinate -> cell index + 4 bilinear corner weights (half2 splats).
static __device__ __forceinline__ void coordw(float x, float y, int* cell, __half2* W)
{
    float fx = fminf(fmaxf(fmaf(x, 7.5f, 7.5f), 0.0f), 15.0f);
    float fy = fminf(fmaxf(fmaf(y, 7.5f, 7.5f), 0.0f), 15.0f);
    int x0 = (int)fx; if (x0 > 14) x0 = 14;
    int y0 = (int)fy; if (y0 > 14) y0 = 14;
    float wx = fx - (float)x0;
    float wy = fy - (float)y0;
    float w11 = wx * wy;
    W[0] = __float2half2_rn(1.0f - wx - wy + w11);
    W[1] = __float2half2_rn(wx - w11);
    W[2] = __float2half2_rn(wy - w11);
    W[3] = __float2half2_rn(w11);
    *cell = (y0 << 4) + x0;
}

__global__ __launch_bounds__(BLOCK, 4) void camfield_kernel(
    const float* __restrict__ xy,
    const uint32_t* __restrict__ packed,   // pre-packed 24 KB grid image (ws)
    const float* __restrict__ w_in,
    const float* __restrict__ b_in,
    const float* __restrict__ w_h,
    const float* __restrict__ b_h,
    const float* __restrict__ w_out,
    const float* __restrict__ b_out,
    float* __restrict__ out)
{
    // LDS mirror of the packed image: sg[l][cell][12 dwords] = 24 KB.
    __shared__ __align__(16) uint32_t sg[2][256][12];

    const int tid = threadIdx.x;

    // prefetch this thread's 4 points BEFORE staging (HBM latency hides
    // under the copy + __syncthreads)
    const int p0 = (blockIdx.x * BLOCK + tid) * PPT;
    const float4* xv = (const float4*)(xy + 2 * p0);
    float4 q0 = xv[0];
    float4 q1 = xv[1];

    // staging = flat copy of 1536 uint4 (L2-resident after first blocks)
    {
        const uint4* src = (const uint4*)packed;
        uint4* dst = (uint4*)&sg[0][0][0];
#pragma unroll
        for (int i = 0; i < 6; ++i)
            dst[tid + 256 * i] = src[tid + 256 * i];
    }

    // weights: everything wave-uniform pinned to SGPRs except b_in (VGPR),
    // so each VALU op reads at most ONE scalar operand.
    float Win0[6], Win1[6], Bin[6], Wh[6][6], Bh[6], Wo[3][6], Bo[3];
#pragma unroll
    for (int j = 0; j < 6; ++j) {
        Win0[j] = rfl(w_in[2 * j]);
        Win1[j] = rfl(w_in[2 * j + 1]);
        Bin[j]  = b_in[j];
        Bh[j]   = rfl(b_h[j]);
#pragma unroll
        for (int k = 0; k < 6; ++k) Wh[j][k] = rfl(w_h[6 * j + k]);
    }
#pragma unroll
    for (int j = 0; j < 3; ++j) {
        Bo[j] = rfl(b_out[j]);
#pragma unroll
        for (int k = 0; k < 6; ++k) Wo[j][k] = rfl(w_out[6 * j + k]);
    }

    __syncthreads();

    float* ob = out + 3 * p0;   // 48B-aligned (p0 multiple of 4)

#pragma unroll
    for (int pp = 0; pp < 2; ++pp) {
        const float xa = (pp == 0) ? q0.x : q1.x;
        const float ya = (pp == 0) ? q0.y : q1.y;
        const float xb = (pp == 0) ? q0.z : q1.z;
        const float yb = (pp == 0) ? q0.w : q1.w;
        const f32x2 X = { xa, xb };
        const f32x2 Y = { ya, yb };

        int cellA, cellB;
        __half2 WA[4], WB[4];
        coordw(xa, ya, &cellA, WA);
        coordw(xb, yb, &cellB, WB);
        const uint4* cA = (const uint4*)&sg[0][cellA][0];
        const uint4* cB = (const uint4*)&sg[0][cellB][0];

        // ---- layer 0: input-layer math is independent of the grid reads,
        // LN-prep is independent of point B's interp -> latency overlap.
        f32x2 h2[6];
#pragma unroll
        for (int j = 0; j < 6; ++j)
            h2[j] = silu2(fma2(X, (f32x2)Win0[j], fma2(Y, (f32x2)Win1[j], (f32x2)Bin[j])));

        f32x2 G[6], Bb[6];
        interp_point(cA, 0, WA, G, Bb, 0);
        f32x2 d[6], rs;
        ln2_prep(h2, d, &rs);
        interp_point(cB, 0, WB, G, Bb, 1);
#pragma unroll
        for (int j = 0; j < 6; ++j)
            h2[j] = fma2(G[j], d[j] * rs, Bb[j]);

        // ---- layer 1: hidden matmul overlaps point A's interp latency.
        f32x2 t2[6];
#pragma unroll
        for (int j = 0; j < 6; ++j) {
            f32x2 a = (f32x2)Bh[j];
#pragma unroll
            for (int k = 0; k < 6; ++k) a = fma2(h2[k], (f32x2)Wh[j][k], a);
            t2[j] = silu2(a);
        }
        interp_point(cA, 768, WA, G, Bb, 0);
        ln2_prep(t2, d, &rs);
        interp_point(cB, 768, WB, G, Bb, 1);
#pragma unroll
        for (int j = 0; j < 6; ++j)
            t2[j] = fma2(G[j], d[j] * rs, Bb[j]);

        // ---- output layer (weights in SGPR), store immediately (no o[12])
        f32x2 ov[3];
#pragma unroll
        for (int j = 0; j < 3; ++j) {
            f32x2 a = (f32x2)Bo[j];
#pragma unroll
            for (int k = 0; k < 6; ++k) a = fma2(t2[k], (f32x2)Wo[j][k], a);
            ov[j] = a;
        }
        if (pp == 0) {
            // floats 0..5: ptA=(ov0.x,ov1.x,ov2.x), ptB=(ov0.y,ov1.y,ov2.y)
            *(float4*)(ob)     = make_float4(ov[0].x, ov[1].x, ov[2].x, ov[0].y);
            *(float2*)(ob + 4) = make_float2(ov[1].y, ov[2].y);
        } else {
            // floats 6..11 (byte 24: float2; byte 32: float4 — both aligned)
            *(float2*)(ob + 6) = make_float2(ov[0].x, ov[1].x);
            *(float4*)(ob + 8) = make_float4(ov[2].x, ov[0].y, ov[1].y, ov[2].y);
        }
    }
}

extern "C" void kernel_launch(void* const* d_in, const int* in_sizes, int n_in,
                              void* d_out, int out_size, void* d_ws, size_t ws_size,
                              hipStream_t stream) {
    // Stage 1: pack the 24 KB grid image once (12 blocks x 256 = 3072 items).
    pack_kernel<<<12, 256, 0, stream>>>(
        (const float*)d_in[1],  // gamma
        (const float*)d_in[2],  // beta
        (const float*)d_in[9],  // ln_w
        (const float*)d_in[10], // ln_b
        (uint32_t*)d_ws);
    // Stage 2: main kernel copies the image to LDS and evaluates the field.
    camfield_kernel<<<NBLK, BLOCK, 0, stream>>>(
        (const float*)d_in[0],  // xy
        (const uint32_t*)d_ws,  // packed grids
        (const float*)d_in[3],  // w_in
        (const float*)d_in[4],  // b_in
        (const float*)d_in[5],  // w_h
        (const float*)d_in[6],  // b_h
        (const float*)d_in[7],  // w_out
        (const float*)d_in[8],  // b_out
        (float*)d_out);
}

// Round 7
// 103.141 us; speedup vs baseline: 1.0182x; 1.0182x over previous
//
#include <hip/hip_runtime.h>
#include <hip/hip_fp16.h>
#include <stdint.h>

#define NPTS 2097152
#define BLOCK 256
#define PPT 4
#define NBLK (NPTS / (BLOCK * PPT))   // 2048 blocks

typedef float f32x2 __attribute__((ext_vector_type(2)));

// Pin a wave-uniform float to an SGPR (frees a VGPR; VOP3P allows 1 scalar src)
static __device__ __forceinline__ float rfl(float v) {
    return __int_as_float(__builtin_amdgcn_readfirstlane(__float_as_int(v)));
}
static __device__ __forceinline__ __half2 u2h(uint32_t u) {
    union { uint32_t i; __half2 h; } v; v.i = u; return v.h;
}
static __device__ __forceinline__ uint32_t h2u(__half2 h) {
    union { __half2 h; uint32_t i; } v; v.h = h; return v.i;
}
static __device__ __forceinline__ f32x2 fma2(f32x2 a, f32x2 b, f32x2 c) {
    return __builtin_elementwise_fma(a, b, c);   // -> v_pk_fma_f32
}
// silu on a point-pair; numerics identical to scalar __expf path
static __device__ __forceinline__ f32x2 silu2(f32x2 v) {
    f32x2 t = v * (-1.4426950408889634f);
    f32x2 e = { __builtin_amdgcn_exp2f(t.x), __builtin_amdgcn_exp2f(t.y) };
    f32x2 d = e + 1.0f;
    f32x2 r = { __builtin_amdgcn_rcpf(d.x), __builtin_amdgcn_rcpf(d.y) };
    return v * r;
}
// LayerNorm (LN affine pre-folded into g/b), packed across a point-pair
static __device__ __forceinline__ void ln2_apply(f32x2* h, const f32x2* g, const f32x2* b)
{
    f32x2 mu = (h[0] + h[1] + h[2] + h[3] + h[4] + h[5]) * (1.0f / 6.0f);
    f32x2 d[6];
    f32x2 var = (f32x2)0.0f;
#pragma unroll
    for (int j = 0; j < 6; ++j) { d[j] = h[j] - mu; var = fma2(d[j], d[j], var); }
    f32x2 vv = var * (1.0f / 6.0f) + 1e-5f;
    f32x2 rs = { __builtin_amdgcn_rsqf(vv.x), __builtin_amdgcn_rsqf(vv.y) };
#pragma unroll
    for (int j = 0; j < 6; ++j)
        h[j] = fma2(g[j], d[j] * rs, b[j]);
}

// ---------------------------------------------------------------------------
// Pre-kernel: build the packed half2 grid image ONCE into workspace.
// Layout (dwords): idx = (l*256 + cell)*12 + slot, slot = {A0,B0,...,A5,B5}.
//   slots s<3  : gamma' = gamma * ln_w     (channel pairs 2s,2s+1)
//   slots s>=3 : beta'  = gamma * ln_b + beta
// A = value at (y,x), B = value at (y,x+1 clamped). 6144 dwords = 24 KB.
// ---------------------------------------------------------------------------
__global__ __launch_bounds__(256) void pack_kernel(
    const float* __restrict__ gamma,
    const float* __restrict__ beta,
    const float* __restrict__ ln_w,
    const float* __restrict__ ln_b,
    uint32_t* __restrict__ ws)
{
    int idx = blockIdx.x * 256 + threadIdx.x;   // 12 blocks x 256 = 3072 items
    if (idx >= 3072) return;
    int l = (idx >= 1536) ? 1 : 0;
    int r = idx - l * 1536;            // 0..1535
    int s = r >> 8;                    // pair 0..5
    int cell = r & 255;
    int x = cell & 15;
    int x1 = (x < 15) ? x + 1 : 15;    // border clamp baked into B
    int rowb = cell - x;               // y*16
    int ch0 = (s < 3) ? 2 * s : 2 * (s - 3);
    const float* gsrc = gamma + l * 1536 + ch0 * 256;
    float ga_lo = gsrc[rowb + x];
    float ga_hi = gsrc[256 + rowb + x];
    float gb_lo = gsrc[rowb + x1];
    float gb_hi = gsrc[256 + rowb + x1];
    float a_lo, a_hi, b_lo, b_hi;
    if (s < 3) {
        float w_lo = ln_w[6 * l + ch0];
        float w_hi = ln_w[6 * l + ch0 + 1];
        a_lo = ga_lo * w_lo; a_hi = ga_hi * w_hi;
        b_lo = gb_lo * w_lo; b_hi = gb_hi * w_hi;
    } else {
        const float* bsrc = beta + l * 1536 + ch0 * 256;
        float nb_lo = ln_b[6 * l + ch0];
        float nb_hi = ln_b[6 * l + ch0 + 1];
        a_lo = fmaf(ga_lo, nb_lo, bsrc[rowb + x]);
        a_hi = fmaf(ga_hi, nb_hi, bsrc[256 + rowb + x]);
        b_lo = fmaf(gb_lo, nb_lo, bsrc[rowb + x1]);
        b_hi = fmaf(gb_hi, nb_hi, bsrc[256 + rowb + x1]);
    }
    uint32_t* dst = ws + (l * 256 + cell) * 12 + 2 * s;
    dst[0] = h2u(__floats2half2_rn(a_lo, a_hi));
    dst[1] = h2u(__floats2half2_rn(b_lo, b_hi));
}

// Bilinear-interp 6 channel-pairs from one cell's 6 b128 words; writes
// component c (0/1, literal after unroll) of the pair-packed g/b vectors.
static __device__ __forceinline__ void interp6_c(
    const uint4* u,
    __half2 W00, __half2 W01, __half2 W10, __half2 W11,
    f32x2* g, f32x2* b, int c)
{
    uint32_t A[6]  = { u[0].x, u[0].z, u[1].x, u[1].z, u[2].x, u[2].z };
    uint32_t Bv[6] = { u[0].y, u[0].w, u[1].y, u[1].w, u[2].y, u[2].w };
    uint32_t C[6]  = { u[3].x, u[3].z, u[4].x, u[4].z, u[5].x, u[5].z };
    uint32_t D[6]  = { u[3].y, u[3].w, u[4].y, u[4].w, u[5].y, u[5].w };
#pragma unroll
    for (int s = 0; s < 6; ++s) {
        __half2 acc = __hmul2(u2h(A[s]), W00);
        acc = __hfma2(u2h(Bv[s]), W01, acc);
        acc = __hfma2(u2h(C[s]), W10, acc);
        acc = __hfma2(u2h(D[s]), W11, acc);
        float2 r = __half22float2(acc);
        if (s < 3) { g[2 * s][c] = r.x; g[2 * s + 1][c] = r.y; }
        else       { b[2 * (s - 3)][c] = r.x; b[2 * (s - 3) + 1][c] = r.y; }
    }
}

__global__ __launch_bounds__(BLOCK, 4) void camfield_kernel(
    const float* __restrict__ xy,
    const uint32_t* __restrict__ packed,   // pre-packed 24 KB grid image (ws)
    const float* __restrict__ w_in,
    const float* __restrict__ b_in,
    const float* __restrict__ w_h,
    const float* __restrict__ b_h,
    const float* __restrict__ w_out,
    const float* __restrict__ b_out,
    float* __restrict__ out)
{
    // LDS mirror of the packed image: sg[l][cell][12 dwords] = 24 KB.
    __shared__ __align__(16) uint32_t sg[2][256][12];

    const int tid = threadIdx.x;

    // prefetch this thread's 4 points BEFORE staging (HBM latency hides
    // under the copy + __syncthreads)
    const int p0 = (blockIdx.x * BLOCK + tid) * PPT;
    const float4* xv = (const float4*)(xy + 2 * p0);
    float4 q0 = xv[0];
    float4 q1 = xv[1];

    // staging = flat copy of 1536 uint4 (L2-resident after first blocks)
    {
        const uint4* src = (const uint4*)packed;
        uint4* dst = (uint4*)&sg[0][0][0];
#pragma unroll
        for (int i = 0; i < 6; ++i)
            dst[tid + 256 * i] = src[tid + 256 * i];
    }

    // weights: input layer in VGPRs (18); Wh/Bh/Wo/Bo pinned to SGPRs (63)
    float Win0[6], Win1[6], Bin[6], Wh[6][6], Bh[6], Wo[3][6], Bo[3];
#pragma unroll
    for (int j = 0; j < 6; ++j) {
        Win0[j] = w_in[2 * j];
        Win1[j] = w_in[2 * j + 1];
        Bin[j]  = b_in[j];
        Bh[j]   = rfl(b_h[j]);
#pragma unroll
        for (int k = 0; k < 6; ++k) Wh[j][k] = rfl(w_h[6 * j + k]);
    }
#pragma unroll
    for (int j = 0; j < 3; ++j) {
        Bo[j] = rfl(b_out[j]);
#pragma unroll
        for (int k = 0; k < 6; ++k) Wo[j][k] = rfl(w_out[6 * j + k]);
    }

    __syncthreads();

    float xs[4] = { q0.x, q0.z, q1.x, q1.z };
    float ys[4] = { q0.y, q0.w, q1.y, q1.w };

    float o[12];

#pragma unroll
    for (int pp = 0; pp < 2; ++pp) {
        // ---- per-point scalar coordinate math (int/addr can't pack)
        __half2 Wq[2][4];
        const uint4* c4[2];
        f32x2 X, Y;
#pragma unroll
        for (int c = 0; c < 2; ++c) {
            const int p = 2 * pp + c;
            const float x = xs[p];
            const float y = ys[p];
            X[c] = x; Y[c] = y;
            float fx = fminf(fmaxf(fmaf(x, 7.5f, 7.5f), 0.0f), 15.0f);
            float fy = fminf(fmaxf(fmaf(y, 7.5f, 7.5f), 0.0f), 15.0f);
            int x0 = (int)fx; if (x0 > 14) x0 = 14;
            int y0 = (int)fy; if (y0 > 14) y0 = 14;
            float wx = fx - (float)x0;
            float wy = fy - (float)y0;
            float w11f = wx * wy;
            float w10f = wy - w11f;
            float w01f = wx - w11f;
            float w00f = 1.0f - wx - wy + w11f;
            Wq[c][0] = __float2half2_rn(w00f);
            Wq[c][1] = __float2half2_rn(w01f);
            Wq[c][2] = __float2half2_rn(w10f);
            Wq[c][3] = __float2half2_rn(w11f);
            c4[c] = (const uint4*)&sg[0][(y0 << 4) + x0][0];
        }

        // ---- layer-0 LDS lines for both points (12 b128, issued together)
        uint4 u[2][6];
#pragma unroll
        for (int c = 0; c < 2; ++c) {
            u[c][0] = c4[c][0];  u[c][1] = c4[c][1];  u[c][2] = c4[c][2];
            u[c][3] = c4[c][48]; u[c][4] = c4[c][49]; u[c][5] = c4[c][50];
        }

        // packed input layer (hides LDS latency): h = silu(x*W0 + y*W1 + B)
        f32x2 h2[6];
#pragma unroll
        for (int j = 0; j < 6; ++j)
            h2[j] = silu2(fma2(X, (f32x2)Win0[j], fma2(Y, (f32x2)Win1[j], (f32x2)Bin[j])));

        f32x2 G[6], Bb[6];
        interp6_c(u[0], Wq[0][0], Wq[0][1], Wq[0][2], Wq[0][3], G, Bb, 0);
        interp6_c(u[1], Wq[1][0], Wq[1][1], Wq[1][2], Wq[1][3], G, Bb, 1);
        ln2_apply(h2, G, Bb);

        // ---- layer-1 LDS lines (sg[1] = +768 uint4), issued before hidden
        uint4 v[2][6];
#pragma unroll
        for (int c = 0; c < 2; ++c) {
            v[c][0] = c4[c][768]; v[c][1] = c4[c][769]; v[c][2] = c4[c][770];
            v[c][3] = c4[c][816]; v[c][4] = c4[c][817]; v[c][5] = c4[c][818];
        }

        // packed hidden layer (hides LDS latency; weights are SGPR splats)
        f32x2 t2[6];
#pragma unroll
        for (int j = 0; j < 6; ++j) {
            f32x2 a = (f32x2)Bh[j];
#pragma unroll
            for (int k = 0; k < 6; ++k) a = fma2(h2[k], (f32x2)Wh[j][k], a);
            t2[j] = silu2(a);
        }

        interp6_c(v[0], Wq[0][0], Wq[0][1], Wq[0][2], Wq[0][3], G, Bb, 0);
        interp6_c(v[1], Wq[1][0], Wq[1][1], Wq[1][2], Wq[1][3], G, Bb, 1);
        ln2_apply(t2, G, Bb);

        // packed output layer
#pragma unroll
        for (int j = 0; j < 3; ++j) {
            f32x2 a = (f32x2)Bo[j];
#pragma unroll
            for (int k = 0; k < 6; ++k) a = fma2(t2[k], (f32x2)Wo[j][k], a);
            o[3 * (2 * pp) + j]     = a.x;
            o[3 * (2 * pp + 1) + j] = a.y;
        }
    }

    // store 12 fp32 = 48 B per thread, 16B-aligned
    float4* op = (float4*)(out + 3 * p0);
#pragma unroll
    for (int q = 0; q < 3; ++q)
        op[q] = make_float4(o[4 * q], o[4 * q + 1], o[4 * q + 2], o[4 * q + 3]);
}

extern "C" void kernel_launch(void* const* d_in, const int* in_sizes, int n_in,
                              void* d_out, int out_size, void* d_ws, size_t ws_size,
                              hipStream_t stream) {
    // Stage 1: pack the 24 KB grid image once (12 blocks x 256 = 3072 items).
    pack_kernel<<<12, 256, 0, stream>>>(
        (const float*)d_in[1],  // gamma
        (const float*)d_in[2],  // beta
        (const float*)d_in[9],  // ln_w
        (const float*)d_in[10], // ln_b
        (uint32_t*)d_ws);
    // Stage 2: main kernel copies the image to LDS and evaluates the field.
    camfield_kernel<<<NBLK, BLOCK, 0, stream>>>(
        (const float*)d_in[0],  // xy
        (const uint32_t*)d_ws,  // packed grids
        (const float*)d_in[3],  // w_in
        (const float*)d_in[4],  // b_in
        (const float*)d_in[5],  // w_h
        (const float*)d_in[6],  // b_h
        (const float*)d_in[7],  // w_out
        (const float*)d_in[8],  // b_out
        (float*)d_out);
}